// Round 1
// baseline (10477.369 us; speedup 1.0000x reference)
//
#include <hip/hip_runtime.h>
#include <stdint.h>

// LSTM (buggy-reference semantics): c_t = tanh(xg+Wgh c_{t-1}) * sigm(xi+Wih c_{t-1})
//                                   h_t = tanh(c_t) * sigm(xo+Woh c_{t-1});  f-gate dead.
// Phase 1: cast W*x to bf16.  Phase 2: big parallel GEMM for X = W*x @ emb^T + b (bf16 out).
// Phase 3: persistent 128-block kernel, custom device barrier per timestep.

#define T_ 512
#define B_ 64
#define E_ 512
#define H_ 1024
#define NBLK 128
#define QS ((size_t)T_ * B_ * H_)   // per-gate stride in X

typedef short bf16x8 __attribute__((ext_vector_type(8)));
typedef float f32x4  __attribute__((ext_vector_type(4)));
typedef float f32x16 __attribute__((ext_vector_type(16)));

__device__ __forceinline__ unsigned int f2bf(float f) {
    unsigned int u = __builtin_bit_cast(unsigned int, f);
    return (u + 0x7fffu + ((u >> 16) & 1u)) >> 16;   // RNE
}
__device__ __forceinline__ float bf2f(unsigned int s) {
    unsigned int u = (s & 0xffffu) << 16;
    return __builtin_bit_cast(float, u);
}
__device__ __forceinline__ float fsigm(float x) { return 1.f / (1.f + __expf(-x)); }
__device__ __forceinline__ float ftanh(float x) { float e = __expf(2.f * x); return 1.f - 2.f / (e + 1.f); }

// ---------------- Phase 1: cast Wgx/Wix/Wox -> bf16 [3][H][E] ----------------
__global__ __launch_bounds__(256) void cast_w1(const float* __restrict__ wg,
                                               const float* __restrict__ wi,
                                               const float* __restrict__ wo,
                                               unsigned short* __restrict__ dst) {
    int idx = blockIdx.x * 256 + threadIdx.x;      // each thread: 4 floats
    const int per = H_ * E_ / 4;                   // 131072
    int q = idx / per;
    int loc = (idx - q * per) * 4;
    const float* src = (q == 0) ? wg : (q == 1) ? wi : wo;
    float4 v = *(const float4*)(src + loc);
    uint2 p;
    p.x = f2bf(v.x) | (f2bf(v.y) << 16);
    p.y = f2bf(v.z) | (f2bf(v.w) << 16);
    *(uint2*)(dst + (size_t)idx * 4) = p;
}

// ---------------- Phase 2: X[q][t][b][h] = (Wq @ emb[t]^T)[h][b] + bq[h], bf16 ----------------
// block = (t, h-tile of 128); 4 waves, each 32 h-rows x 64 b; 32x32x16 MFMA; K=512.
__global__ __launch_bounds__(256) void gemm_x(const float* __restrict__ emb,          // [T][B][E] f32
                                              const unsigned short* __restrict__ Wb1, // [3][H][E] bf16
                                              const float* __restrict__ bg,
                                              const float* __restrict__ bi,
                                              const float* __restrict__ bo,
                                              unsigned short* __restrict__ X) {       // [3][T][B][H] bf16
    const int t   = blockIdx.x >> 3;
    const int hb  = (blockIdx.x & 7) << 7;
    const int tid = threadIdx.x;
    __shared__ unsigned short eb[B_ * E_];   // 64KB, row b = 1024B, XOR-swizzled

    // stage emb[t] (f32) -> bf16 LDS, swizzled
    const float* et = emb + (size_t)t * (B_ * E_);
    #pragma unroll
    for (int it = 0; it < 32; ++it) {
        int F = (it * 256 + tid) * 4;          // float index in [0, 32768)
        int b = F >> 9, e = F & 511;
        float4 v = *(const float4*)(et + F);
        uint2 p;
        p.x = f2bf(v.x) | (f2bf(v.y) << 16);
        p.y = f2bf(v.z) | (f2bf(v.w) << 16);
        *(uint2*)((char*)eb + b * 1024 + ((e * 2) ^ ((b & 7) << 4))) = p;
    }
    __syncthreads();

    const int w = tid >> 6, l = tid & 63;
    const int l31 = l & 31, l5 = l >> 5;
    const int hw = hb + (w << 5);

    f32x16 acc[3][2];
    #pragma unroll
    for (int q = 0; q < 3; ++q)
        #pragma unroll
        for (int n = 0; n < 2; ++n)
            #pragma unroll
            for (int k = 0; k < 16; ++k) acc[q][n][k] = 0.f;

    const unsigned short* Ar0 = Wb1 + ((size_t)0 * H_ + hw + l31) * E_ + l5 * 8;
    const unsigned short* Ar1 = Wb1 + ((size_t)1 * H_ + hw + l31) * E_ + l5 * 8;
    const unsigned short* Ar2 = Wb1 + ((size_t)2 * H_ + hw + l31) * E_ + l5 * 8;

    for (int s = 0; s < 32; ++s) {
        int r0 = l31, r1 = 32 + l31;
        int c0 = (s * 32 + l5 * 16) ^ ((r0 & 7) << 4);
        int c1 = (s * 32 + l5 * 16) ^ ((r1 & 7) << 4);
        bf16x8 Bf0 = *(const bf16x8*)((const char*)eb + r0 * 1024 + c0);
        bf16x8 Bf1 = *(const bf16x8*)((const char*)eb + r1 * 1024 + c1);
        bf16x8 a0 = *(const bf16x8*)(Ar0 + s * 16);
        bf16x8 a1 = *(const bf16x8*)(Ar1 + s * 16);
        bf16x8 a2 = *(const bf16x8*)(Ar2 + s * 16);
        acc[0][0] = __builtin_amdgcn_mfma_f32_32x32x16_bf16(a0, Bf0, acc[0][0], 0, 0, 0);
        acc[0][1] = __builtin_amdgcn_mfma_f32_32x32x16_bf16(a0, Bf1, acc[0][1], 0, 0, 0);
        acc[1][0] = __builtin_amdgcn_mfma_f32_32x32x16_bf16(a1, Bf0, acc[1][0], 0, 0, 0);
        acc[1][1] = __builtin_amdgcn_mfma_f32_32x32x16_bf16(a1, Bf1, acc[1][1], 0, 0, 0);
        acc[2][0] = __builtin_amdgcn_mfma_f32_32x32x16_bf16(a2, Bf0, acc[2][0], 0, 0, 0);
        acc[2][1] = __builtin_amdgcn_mfma_f32_32x32x16_bf16(a2, Bf1, acc[2][1], 0, 0, 0);
    }

    const float* bias[3] = {bg, bi, bo};
    #pragma unroll
    for (int q = 0; q < 3; ++q) {
        #pragma unroll
        for (int g4 = 0; g4 < 4; ++g4) {
            int h = hw + g4 * 8 + l5 * 4;  // C row = (reg&3) + 8*(reg>>2) + 4*(lane>>5)
            float4 bv = *(const float4*)(bias[q] + h);
            #pragma unroll
            for (int n = 0; n < 2; ++n) {
                float v0 = acc[q][n][g4 * 4 + 0] + bv.x;
                float v1 = acc[q][n][g4 * 4 + 1] + bv.y;
                float v2 = acc[q][n][g4 * 4 + 2] + bv.z;
                float v3 = acc[q][n][g4 * 4 + 3] + bv.w;
                uint2 p;
                p.x = f2bf(v0) | (f2bf(v1) << 16);
                p.y = f2bf(v2) | (f2bf(v3) << 16);
                size_t o = ((size_t)q * T_ + t) * (size_t)(B_ * H_) + (size_t)((n << 5) + l31) * H_ + h;
                *(uint2*)(X + o) = p;
            }
        }
    }
}

// ---------------- Phase 3: persistent recurrence ----------------
// 128 blocks x 512 thr. Even blocks (A): g,i -> c_t. Odd blocks (B): o_t + emit h_{t-1}.
// Block m: 16 h-rows [16m,16m+16). Waves: (khalf = w>>2) x (ntile = w&3); both gates per A-wave.
// W fragments live in registers across all 512 steps; c^T [64b][1024h] bf16 double-buffered in ws.
__global__ __launch_bounds__(512) void lstm_rec(const float* __restrict__ Wgh,
                                                const float* __restrict__ Wih,
                                                const float* __restrict__ Woh,
                                                const unsigned short* __restrict__ X,
                                                unsigned short* cbuf,     // [2][B][H]
                                                unsigned int* ctr,
                                                float* __restrict__ out) { // [T][B][H] f32
    const int bid = blockIdx.x;
    const bool isA = (bid & 1) == 0;
    const int m = bid >> 1;
    const int h0 = m << 4;
    const int tid = threadIdx.x;
    const int w = tid >> 6, l = tid & 63;
    const int kh = w >> 2, n = w & 3;
    const int l15 = l & 15, l4 = l >> 4;
    const int kbase = kh << 9;            // 0 or 512
    const int bcol = (n << 4) + l15;      // b in [0,64)
    const int hrow = h0 + (l4 << 2);      // C row base: 4*(lane>>4); + reg j

    __shared__ float red[4][2][64][4];    // khalf reduction scratch, 8KB

    // ---- preload W fragments (A-operand, reg-stationary) ----
    bf16x8 A0[16], A1[16];
    {
        const float* W0 = isA ? Wgh : Woh;
        const float* r0 = W0 + (size_t)(h0 + l15) * H_ + kbase + l4 * 8;
        #pragma unroll
        for (int s = 0; s < 16; ++s) {
            float4 u = *(const float4*)(r0 + s * 32);
            float4 v = *(const float4*)(r0 + s * 32 + 4);
            bf16x8 a;
            a[0] = (short)f2bf(u.x); a[1] = (short)f2bf(u.y); a[2] = (short)f2bf(u.z); a[3] = (short)f2bf(u.w);
            a[4] = (short)f2bf(v.x); a[5] = (short)f2bf(v.y); a[6] = (short)f2bf(v.z); a[7] = (short)f2bf(v.w);
            A0[s] = a;
        }
        if (isA) {
            const float* r1 = Wih + (size_t)(h0 + l15) * H_ + kbase + l4 * 8;
            #pragma unroll
            for (int s = 0; s < 16; ++s) {
                float4 u = *(const float4*)(r1 + s * 32);
                float4 v = *(const float4*)(r1 + s * 32 + 4);
                bf16x8 a;
                a[0] = (short)f2bf(u.x); a[1] = (short)f2bf(u.y); a[2] = (short)f2bf(u.z); a[3] = (short)f2bf(u.w);
                a[4] = (short)f2bf(v.x); a[5] = (short)f2bf(v.y); a[6] = (short)f2bf(v.z); a[7] = (short)f2bf(v.w);
                A1[s] = a;
            }
        }
    }

    float4 o_prev = {0.f, 0.f, 0.f, 0.f};

    for (int t = 0; t < T_; ++t) {
        // ---- wait for c_{t-1} (all NBLK blocks arrived step t-1) ----
        if (tid == 0) {
            unsigned int tgt = (unsigned int)t * NBLK;
            while (__hip_atomic_load(ctr, __ATOMIC_RELAXED, __HIP_MEMORY_SCOPE_AGENT) < tgt)
                __builtin_amdgcn_s_sleep(1);
        }
        __syncthreads();
        __builtin_amdgcn_fence(__ATOMIC_ACQUIRE, "agent");

        const unsigned short* cprev = cbuf + (size_t)(t & 1) * (B_ * H_);
        unsigned short* cnext = cbuf + (size_t)((t + 1) & 1) * (B_ * H_);

        // ---- B fragments: c^T[b][k], 16 x b128 loads (all outstanding) ----
        const unsigned short* bp = cprev + (size_t)bcol * H_ + kbase + l4 * 8;
        bf16x8 bf[16];
        #pragma unroll
        for (int s = 0; s < 16; ++s) bf[s] = *(const bf16x8*)(bp + s * 32);

        f32x4 acc0 = {0.f, 0.f, 0.f, 0.f}, acc1 = {0.f, 0.f, 0.f, 0.f};
        if (isA) {
            #pragma unroll
            for (int s = 0; s < 16; ++s) {
                acc0 = __builtin_amdgcn_mfma_f32_16x16x32_bf16(A0[s], bf[s], acc0, 0, 0, 0);
                acc1 = __builtin_amdgcn_mfma_f32_16x16x32_bf16(A1[s], bf[s], acc1, 0, 0, 0);
            }
        } else {
            #pragma unroll
            for (int s = 0; s < 16; ++s)
                acc0 = __builtin_amdgcn_mfma_f32_16x16x32_bf16(A0[s], bf[s], acc0, 0, 0, 0);
        }

        // ---- khalf reduction via LDS ----
        if (kh == 1) {
            *(f32x4*)&red[n][0][l][0] = acc0;
            if (isA) *(f32x4*)&red[n][1][l][0] = acc1;
        }
        __syncthreads();
        if (kh == 0) {
            acc0 += *(const f32x4*)&red[n][0][l][0];
            if (isA) acc1 += *(const f32x4*)&red[n][1][l][0];

            size_t xb = ((size_t)t * B_ + bcol) * H_ + hrow;
            if (isA) {
                uint2 pg = *(const uint2*)(X + xb);
                uint2 pi = *(const uint2*)(X + xb + QS);
                float g0 = ftanh(acc0[0] + bf2f(pg.x));
                float g1 = ftanh(acc0[1] + bf2f(pg.x >> 16));
                float g2 = ftanh(acc0[2] + bf2f(pg.y));
                float g3 = ftanh(acc0[3] + bf2f(pg.y >> 16));
                float i0 = fsigm(acc1[0] + bf2f(pi.x));
                float i1 = fsigm(acc1[1] + bf2f(pi.x >> 16));
                float i2 = fsigm(acc1[2] + bf2f(pi.y));
                float i3 = fsigm(acc1[3] + bf2f(pi.y >> 16));
                uint2 pc;
                pc.x = f2bf(g0 * i0) | (f2bf(g1 * i1) << 16);
                pc.y = f2bf(g2 * i2) | (f2bf(g3 * i3) << 16);
                *(uint2*)(cnext + (size_t)bcol * H_ + hrow) = pc;
            } else {
                uint2 po = *(const uint2*)(X + xb + 2 * QS);
                uint2 pc = *(const uint2*)(cprev + (size_t)bcol * H_ + hrow);
                if (t > 0) {
                    float4 hv;
                    hv.x = ftanh(bf2f(pc.x)) * o_prev.x;
                    hv.y = ftanh(bf2f(pc.x >> 16)) * o_prev.y;
                    hv.z = ftanh(bf2f(pc.y)) * o_prev.z;
                    hv.w = ftanh(bf2f(pc.y >> 16)) * o_prev.w;
                    *(float4*)(out + ((size_t)(t - 1) * B_ + bcol) * H_ + hrow) = hv;
                }
                o_prev.x = fsigm(acc0[0] + bf2f(po.x));
                o_prev.y = fsigm(acc0[1] + bf2f(po.x >> 16));
                o_prev.z = fsigm(acc0[2] + bf2f(po.y));
                o_prev.w = fsigm(acc0[3] + bf2f(po.y >> 16));
            }
        }
        // ---- arrive ----
        __syncthreads();
        if (tid == 0) {
            __builtin_amdgcn_fence(__ATOMIC_RELEASE, "agent");
            atomicAdd(ctr, 1u);
        }
    }

    // ---- final h_{T-1} (needs c_{511}, written during step 511) ----
    if (!isA) {
        if (tid == 0) {
            while (__hip_atomic_load(ctr, __ATOMIC_RELAXED, __HIP_MEMORY_SCOPE_AGENT) < (unsigned int)(T_ * NBLK))
                __builtin_amdgcn_s_sleep(1);
        }
        __syncthreads();
        __builtin_amdgcn_fence(__ATOMIC_ACQUIRE, "agent");
        if (kh == 0) {
            const unsigned short* cfin = cbuf;   // c_511 lives in cbuf[(511+1)&1] = cbuf[0]
            uint2 pc = *(const uint2*)(cfin + (size_t)bcol * H_ + hrow);
            float4 hv;
            hv.x = ftanh(bf2f(pc.x)) * o_prev.x;
            hv.y = ftanh(bf2f(pc.x >> 16)) * o_prev.y;
            hv.z = ftanh(bf2f(pc.y)) * o_prev.z;
            hv.w = ftanh(bf2f(pc.y >> 16)) * o_prev.w;
            *(float4*)(out + ((size_t)(T_ - 1) * B_ + bcol) * H_ + hrow) = hv;
        }
    }
}

extern "C" void kernel_launch(void* const* d_in, const int* in_sizes, int n_in,
                              void* d_out, int out_size, void* d_ws, size_t ws_size,
                              hipStream_t stream) {
    const float* emb = (const float*)d_in[0];
    const float* Wgx = (const float*)d_in[1];
    const float* Wgh = (const float*)d_in[2];
    const float* bg  = (const float*)d_in[3];
    const float* Wix = (const float*)d_in[4];
    const float* Wih = (const float*)d_in[5];
    const float* bi  = (const float*)d_in[6];
    // d_in[7..9] = Wfx, Wfh, bf : dead in the reference (c = g*i + 0*f)
    const float* Wox = (const float*)d_in[10];
    const float* Woh = (const float*)d_in[11];
    const float* bo  = (const float*)d_in[12];
    float* out = (float*)d_out;

    char* ws = (char*)d_ws;
    const size_t wb1_bytes = (size_t)3 * H_ * E_ * 2;        //  3.1 MB
    const size_t x_bytes   = (size_t)3 * T_ * B_ * H_ * 2;   // 201.3 MB
    const size_t c_bytes   = (size_t)2 * B_ * H_ * 2;        //  0.25 MB
    unsigned short* Wb1 = (unsigned short*)ws;
    unsigned short* X   = (unsigned short*)(ws + wb1_bytes);
    unsigned short* cb  = (unsigned short*)(ws + wb1_bytes + x_bytes);
    unsigned int*   ctr = (unsigned int*)(ws + wb1_bytes + x_bytes + c_bytes);

    hipMemsetAsync(cb, 0, c_bytes + 256, stream);            // zero c double-buffer + barrier ctr
    cast_w1<<<1536, 256, 0, stream>>>(Wgx, Wix, Wox, Wb1);
    gemm_x<<<T_ * 8, 256, 0, stream>>>(emb, Wb1, bg, bi, bo, X);
    lstm_rec<<<NBLK, 512, 0, stream>>>(Wgh, Wih, Woh, X, cb, ctr, out);
}

// Round 2
// 4655.948 us; speedup vs baseline: 2.2503x; 2.2503x over previous
//
#include <hip/hip_runtime.h>
#include <stdint.h>

// LSTM (buggy-reference semantics): c_t = tanh(xg+Wgh c_{t-1}) * sigm(xi+Wih c_{t-1})
//                                   h_t = tanh(c_t) * sigm(xo+Woh c_{t-1});  f-gate dead.
// Phase 1: cast W*x to bf16.  Phase 2: parallel GEMM X = W*x @ emb^T + b (bf16).
// Phase 3: persistent recurrence, NO agent fences: write-once carry history embedded in
// the (not-yet-written) second half of each out row, system-scope (sc0 sc1, write-through)
// stores for all d_out writes, plain cached loads for reads, per-block progress flags.

#define T_ 512
#define B_ 64
#define E_ 512
#define H_ 1024
#define QS ((size_t)T_ * B_ * H_)     // per-gate stride in X
#define ROWF ((size_t)(B_ * H_))      // floats per out row (65536)
#define CH_OFF (ROWF / 2)             // float offset of chist region inside an out row

typedef short bf16x8 __attribute__((ext_vector_type(8)));
typedef float f32x4  __attribute__((ext_vector_type(4)));
typedef float f32x16 __attribute__((ext_vector_type(16)));

__device__ __forceinline__ unsigned int f2bf(float f) {
    unsigned int u = __builtin_bit_cast(unsigned int, f);
    return (u + 0x7fffu + ((u >> 16) & 1u)) >> 16;   // RNE
}
__device__ __forceinline__ float bf2f(unsigned int s) {
    unsigned int u = (s & 0xffffu) << 16;
    return __builtin_bit_cast(float, u);
}
__device__ __forceinline__ float fsigm(float x) { return 1.f / (1.f + __expf(-x)); }
__device__ __forceinline__ float ftanh(float x) { float e = __expf(2.f * x); return 1.f - 2.f / (e + 1.f); }

__device__ __forceinline__ unsigned ldflag(const unsigned* p) {
    return __hip_atomic_load(p, __ATOMIC_RELAXED, __HIP_MEMORY_SCOPE_SYSTEM);
}
__device__ __forceinline__ void stflag(unsigned* p, unsigned v) {
    __hip_atomic_store(p, v, __ATOMIC_RELAXED, __HIP_MEMORY_SCOPE_SYSTEM);
}
__device__ __forceinline__ void st_sys64(void* p, unsigned long long v) {
    __hip_atomic_store((unsigned long long*)p, v, __ATOMIC_RELAXED, __HIP_MEMORY_SCOPE_SYSTEM);
}
__device__ __forceinline__ unsigned long long pk4bf(float a, float b, float c, float d) {
    return (unsigned long long)(f2bf(a) | (f2bf(b) << 16)) |
           ((unsigned long long)(f2bf(c) | (f2bf(d) << 16)) << 32);
}
__device__ __forceinline__ unsigned long long pk2f(float a, float b) {
    return (unsigned long long)__builtin_bit_cast(unsigned, a) |
           ((unsigned long long)__builtin_bit_cast(unsigned, b) << 32);
}

// ---------------- Phase 1: cast Wgx/Wix/Wox -> bf16 [3][H][E] ----------------
__global__ __launch_bounds__(256) void cast_w1(const float* __restrict__ wg,
                                               const float* __restrict__ wi,
                                               const float* __restrict__ wo,
                                               unsigned short* __restrict__ dst) {
    int idx = blockIdx.x * 256 + threadIdx.x;      // each thread: 4 floats
    const int per = H_ * E_ / 4;                   // 131072
    int q = idx / per;
    int loc = (idx - q * per) * 4;
    const float* src = (q == 0) ? wg : (q == 1) ? wi : wo;
    float4 v = *(const float4*)(src + loc);
    uint2 p;
    p.x = f2bf(v.x) | (f2bf(v.y) << 16);
    p.y = f2bf(v.z) | (f2bf(v.w) << 16);
    *(uint2*)(dst + (size_t)idx * 4) = p;
}

// ---------------- Phase 2: X[q][t][b][h] = (Wq @ emb[t]^T)[h][b] + bq[h], bf16 ----------------
__global__ __launch_bounds__(256) void gemm_x(const float* __restrict__ emb,          // [T][B][E] f32
                                              const unsigned short* __restrict__ Wb1, // [3][H][E] bf16
                                              const float* __restrict__ bg,
                                              const float* __restrict__ bi,
                                              const float* __restrict__ bo,
                                              unsigned short* __restrict__ X) {       // [3][T][B][H] bf16
    const int t   = blockIdx.x >> 3;
    const int hb  = (blockIdx.x & 7) << 7;
    const int tid = threadIdx.x;
    __shared__ unsigned short eb[B_ * E_];   // 64KB, row b = 1024B, XOR-swizzled

    const float* et = emb + (size_t)t * (B_ * E_);
    #pragma unroll
    for (int it = 0; it < 32; ++it) {
        int F = (it * 256 + tid) * 4;
        int b = F >> 9, e = F & 511;
        float4 v = *(const float4*)(et + F);
        uint2 p;
        p.x = f2bf(v.x) | (f2bf(v.y) << 16);
        p.y = f2bf(v.z) | (f2bf(v.w) << 16);
        *(uint2*)((char*)eb + b * 1024 + ((e * 2) ^ ((b & 7) << 4))) = p;
    }
    __syncthreads();

    const int w = tid >> 6, l = tid & 63;
    const int l31 = l & 31, l5 = l >> 5;
    const int hw = hb + (w << 5);

    f32x16 acc[3][2];
    #pragma unroll
    for (int q = 0; q < 3; ++q)
        #pragma unroll
        for (int n = 0; n < 2; ++n)
            #pragma unroll
            for (int k = 0; k < 16; ++k) acc[q][n][k] = 0.f;

    const unsigned short* Ar0 = Wb1 + ((size_t)0 * H_ + hw + l31) * E_ + l5 * 8;
    const unsigned short* Ar1 = Wb1 + ((size_t)1 * H_ + hw + l31) * E_ + l5 * 8;
    const unsigned short* Ar2 = Wb1 + ((size_t)2 * H_ + hw + l31) * E_ + l5 * 8;

    for (int s = 0; s < 32; ++s) {
        int r0 = l31, r1 = 32 + l31;
        int c0 = (s * 32 + l5 * 16) ^ ((r0 & 7) << 4);
        int c1 = (s * 32 + l5 * 16) ^ ((r1 & 7) << 4);
        bf16x8 Bf0 = *(const bf16x8*)((const char*)eb + r0 * 1024 + c0);
        bf16x8 Bf1 = *(const bf16x8*)((const char*)eb + r1 * 1024 + c1);
        bf16x8 a0 = *(const bf16x8*)(Ar0 + s * 16);
        bf16x8 a1 = *(const bf16x8*)(Ar1 + s * 16);
        bf16x8 a2 = *(const bf16x8*)(Ar2 + s * 16);
        acc[0][0] = __builtin_amdgcn_mfma_f32_32x32x16_bf16(a0, Bf0, acc[0][0], 0, 0, 0);
        acc[0][1] = __builtin_amdgcn_mfma_f32_32x32x16_bf16(a0, Bf1, acc[0][1], 0, 0, 0);
        acc[1][0] = __builtin_amdgcn_mfma_f32_32x32x16_bf16(a1, Bf0, acc[1][0], 0, 0, 0);
        acc[1][1] = __builtin_amdgcn_mfma_f32_32x32x16_bf16(a1, Bf1, acc[1][1], 0, 0, 0);
        acc[2][0] = __builtin_amdgcn_mfma_f32_32x32x16_bf16(a2, Bf0, acc[2][0], 0, 0, 0);
        acc[2][1] = __builtin_amdgcn_mfma_f32_32x32x16_bf16(a2, Bf1, acc[2][1], 0, 0, 0);
    }

    const float* bias[3] = {bg, bi, bo};
    #pragma unroll
    for (int q = 0; q < 3; ++q) {
        #pragma unroll
        for (int g4 = 0; g4 < 4; ++g4) {
            int h = hw + g4 * 8 + l5 * 4;
            float4 bv = *(const float4*)(bias[q] + h);
            #pragma unroll
            for (int n = 0; n < 2; ++n) {
                float v0 = acc[q][n][g4 * 4 + 0] + bv.x;
                float v1 = acc[q][n][g4 * 4 + 1] + bv.y;
                float v2 = acc[q][n][g4 * 4 + 2] + bv.z;
                float v3 = acc[q][n][g4 * 4 + 3] + bv.w;
                uint2 p;
                p.x = f2bf(v0) | (f2bf(v1) << 16);
                p.y = f2bf(v2) | (f2bf(v3) << 16);
                size_t o = ((size_t)q * T_ + t) * (size_t)(B_ * H_) + (size_t)((n << 5) + l31) * H_ + h;
                *(uint2*)(X + o) = p;
            }
        }
    }
}

// ---------------- Phase 3: persistent recurrence, fence-free ----------------
// 128 blocks x 256 thr (1/CU). Blocks 0-63 (A): g,i -> c. Blocks 64-127 (B): o + h-emit.
// Block role-j owns h rows [16j,16j+16). Wave w = b-tile (16 cols), full K=1024 per wave.
// chist[t] (carry INTO step t, t=1..511) = bf16[B][H] at out-row t, float offset 32768.
// chist[512] in ws. chist addresses are write-once per launch -> plain cached reads are
// never stale. All d_out stores are system-scope write-through (no dirty L2 lines in
// d_out, so the later h overwrite of the chist region cannot race a writeback).
// Protocol: aflag[j]=t+1 after A-block j stored its chist[t+1] slice (vmcnt-drained).
//           bflag[j]=t+1 after B-block j finished reading chist[t].
//           A step t waits aflags>=t. B step t waits aflags>=t && bflags>=t (B-B lockstep
//           makes overwriting out[t-1] safe vs lagging chist[t-1] readers).
__global__ __launch_bounds__(256) void lstm_rec(const float* __restrict__ Wgh,
                                                const float* __restrict__ Wih,
                                                const float* __restrict__ Woh,
                                                const unsigned short* __restrict__ X,
                                                unsigned short* __restrict__ ch512,
                                                unsigned* __restrict__ aflags,
                                                unsigned* __restrict__ bflags,
                                                float* __restrict__ out) {
    const int bid = blockIdx.x;
    const bool isA = bid < 64;
    const int blk = isA ? bid : bid - 64;
    const int h0 = blk << 4;
    const int tid = threadIdx.x;
    const int l = tid & 63;
    const int w = tid >> 6;
    const int l15 = l & 15, l4 = l >> 4;
    const int bcol = (w << 4) + l15;          // b in [0,64)
    const int hrow = h0 + (l4 << 2);          // + reg j

    // ---- preload recurrent-W fragments (reg-stationary for all 512 steps) ----
    // A-frag lane map (16x16x32): row = h0 + (l&15), k = 32s + 8*(l>>4) + j
    bf16x8 Ag[32], Ai[32];
    {
        const float* r0 = (isA ? Wgh : Woh) + (size_t)(h0 + l15) * H_ + l4 * 8;
        #pragma unroll
        for (int s = 0; s < 32; ++s) {
            float4 u = *(const float4*)(r0 + s * 32);
            float4 v = *(const float4*)(r0 + s * 32 + 4);
            bf16x8 a;
            a[0] = (short)f2bf(u.x); a[1] = (short)f2bf(u.y); a[2] = (short)f2bf(u.z); a[3] = (short)f2bf(u.w);
            a[4] = (short)f2bf(v.x); a[5] = (short)f2bf(v.y); a[6] = (short)f2bf(v.z); a[7] = (short)f2bf(v.w);
            Ag[s] = a;
        }
        if (isA) {
            const float* r1 = Wih + (size_t)(h0 + l15) * H_ + l4 * 8;
            #pragma unroll
            for (int s = 0; s < 32; ++s) {
                float4 u = *(const float4*)(r1 + s * 32);
                float4 v = *(const float4*)(r1 + s * 32 + 4);
                bf16x8 a;
                a[0] = (short)f2bf(u.x); a[1] = (short)f2bf(u.y); a[2] = (short)f2bf(u.z); a[3] = (short)f2bf(u.w);
                a[4] = (short)f2bf(v.x); a[5] = (short)f2bf(v.y); a[6] = (short)f2bf(v.z); a[7] = (short)f2bf(v.w);
                Ai[s] = a;
            }
        }
    }

    if (isA) {
        for (int t = 0; t < T_; ++t) {
            size_t xb = ((size_t)t * B_ + bcol) * H_ + hrow;
            uint2 pg = *(const uint2*)(X + xb);          // hoisted: independent of carry
            uint2 pi = *(const uint2*)(X + xb + QS);

            if (t > 0) {
                if (tid < 64) {
                    while (!__all((int)(ldflag(aflags + tid) >= (unsigned)t)))
                        __builtin_amdgcn_s_sleep(1);
                }
                __syncthreads();
            }

            f32x4 acc0 = {0.f, 0.f, 0.f, 0.f}, acc1 = {0.f, 0.f, 0.f, 0.f};
            if (t > 0) {
                const unsigned short* ct = (const unsigned short*)(out + (size_t)t * ROWF + CH_OFF);
                const unsigned short* bp = ct + (size_t)bcol * H_ + l4 * 8;
                #pragma unroll
                for (int cch = 0; cch < 4; ++cch) {
                    bf16x8 bfr[8];
                    #pragma unroll
                    for (int s = 0; s < 8; ++s) bfr[s] = *(const bf16x8*)(bp + (cch * 8 + s) * 32);
                    #pragma unroll
                    for (int s = 0; s < 8; ++s) {
                        acc0 = __builtin_amdgcn_mfma_f32_16x16x32_bf16(Ag[cch * 8 + s], bfr[s], acc0, 0, 0, 0);
                        acc1 = __builtin_amdgcn_mfma_f32_16x16x32_bf16(Ai[cch * 8 + s], bfr[s], acc1, 0, 0, 0);
                    }
                }
            }

            float g0 = ftanh(acc0[0] + bf2f(pg.x));
            float g1 = ftanh(acc0[1] + bf2f(pg.x >> 16));
            float g2 = ftanh(acc0[2] + bf2f(pg.y));
            float g3 = ftanh(acc0[3] + bf2f(pg.y >> 16));
            float i0 = fsigm(acc1[0] + bf2f(pi.x));
            float i1 = fsigm(acc1[1] + bf2f(pi.x >> 16));
            float i2 = fsigm(acc1[2] + bf2f(pi.y));
            float i3 = fsigm(acc1[3] + bf2f(pi.y >> 16));

            unsigned short* cn = (t == T_ - 1) ? ch512
                               : (unsigned short*)(out + (size_t)(t + 1) * ROWF + CH_OFF);
            st_sys64(cn + (size_t)bcol * H_ + hrow, pk4bf(g0 * i0, g1 * i1, g2 * i2, g3 * i3));

            asm volatile("s_waitcnt vmcnt(0)" ::: "memory");   // per-wave drain before barrier
            __syncthreads();
            if (tid == 0) stflag(aflags + blk, (unsigned)(t + 1));
        }
    } else {
        float4 o_prev = {0.f, 0.f, 0.f, 0.f};
        for (int t = 0; t < T_; ++t) {
            size_t xb = ((size_t)t * B_ + bcol) * H_ + hrow;
            uint2 po = *(const uint2*)(X + xb + 2 * QS);

            if (t > 0) {
                if (tid < 64) {
                    while (!__all((int)(ldflag(aflags + tid) >= (unsigned)t &&
                                        ldflag(bflags + tid) >= (unsigned)t)))
                        __builtin_amdgcn_s_sleep(1);
                }
                __syncthreads();
            }

            f32x4 acc0 = {0.f, 0.f, 0.f, 0.f};
            if (t > 0) {
                const unsigned short* ct = (const unsigned short*)(out + (size_t)t * ROWF + CH_OFF);
                const unsigned short* bp = ct + (size_t)bcol * H_ + l4 * 8;
                #pragma unroll
                for (int cch = 0; cch < 4; ++cch) {
                    bf16x8 bfr[8];
                    #pragma unroll
                    for (int s = 0; s < 8; ++s) bfr[s] = *(const bf16x8*)(bp + (cch * 8 + s) * 32);
                    #pragma unroll
                    for (int s = 0; s < 8; ++s)
                        acc0 = __builtin_amdgcn_mfma_f32_16x16x32_bf16(Ag[cch * 8 + s], bfr[s], acc0, 0, 0, 0);
                }
                // emit h_{t-1} = tanh(c_{t-1}) * o_{t-1};  c_{t-1} = chist[t]
                uint2 pc = *(const uint2*)(ct + (size_t)bcol * H_ + hrow);
                float* op = out + (size_t)(t - 1) * ROWF + (size_t)bcol * H_ + hrow;
                st_sys64(op,     pk2f(ftanh(bf2f(pc.x)) * o_prev.x, ftanh(bf2f(pc.x >> 16)) * o_prev.y));
                st_sys64(op + 2, pk2f(ftanh(bf2f(pc.y)) * o_prev.z, ftanh(bf2f(pc.y >> 16)) * o_prev.w));
            }
            o_prev.x = fsigm(acc0[0] + bf2f(po.x));
            o_prev.y = fsigm(acc0[1] + bf2f(po.x >> 16));
            o_prev.z = fsigm(acc0[2] + bf2f(po.y));
            o_prev.w = fsigm(acc0[3] + bf2f(po.y >> 16));

            __syncthreads();   // chist[t] reads all consumed above -> safe to publish
            if (tid == 0) stflag(bflags + blk, (unsigned)(t + 1));
        }
        // final h_{T-1} from c_511 (= chist[512] in ws)
        if (tid < 64) {
            while (!__all((int)(ldflag(aflags + tid) >= (unsigned)T_ &&
                                ldflag(bflags + tid) >= (unsigned)T_)))
                __builtin_amdgcn_s_sleep(1);
        }
        __syncthreads();
        {
            uint2 pc = *(const uint2*)(ch512 + (size_t)bcol * H_ + hrow);
            float* op = out + (size_t)(T_ - 1) * ROWF + (size_t)bcol * H_ + hrow;
            st_sys64(op,     pk2f(ftanh(bf2f(pc.x)) * o_prev.x, ftanh(bf2f(pc.x >> 16)) * o_prev.y));
            st_sys64(op + 2, pk2f(ftanh(bf2f(pc.y)) * o_prev.z, ftanh(bf2f(pc.y >> 16)) * o_prev.w));
        }
    }
}

extern "C" void kernel_launch(void* const* d_in, const int* in_sizes, int n_in,
                              void* d_out, int out_size, void* d_ws, size_t ws_size,
                              hipStream_t stream) {
    const float* emb = (const float*)d_in[0];
    const float* Wgx = (const float*)d_in[1];
    const float* Wgh = (const float*)d_in[2];
    const float* bg  = (const float*)d_in[3];
    const float* Wix = (const float*)d_in[4];
    const float* Wih = (const float*)d_in[5];
    const float* bi  = (const float*)d_in[6];
    // d_in[7..9] = Wfx, Wfh, bf : dead in the reference (c = g*i + 0*f)
    const float* Wox = (const float*)d_in[10];
    const float* Woh = (const float*)d_in[11];
    const float* bo  = (const float*)d_in[12];
    float* out = (float*)d_out;

    char* ws = (char*)d_ws;
    const size_t wb1_bytes = (size_t)3 * H_ * E_ * 2;        //   3.1 MB
    const size_t x_bytes   = (size_t)3 * T_ * B_ * H_ * 2;   // 201.3 MB
    const size_t c_bytes   = (size_t)B_ * H_ * 2;            // 128 KB (chist[512] only)
    unsigned short* Wb1 = (unsigned short*)ws;
    unsigned short* X   = (unsigned short*)(ws + wb1_bytes);
    unsigned short* c512 = (unsigned short*)(ws + wb1_bytes + x_bytes);
    unsigned* aflags = (unsigned*)(ws + wb1_bytes + x_bytes + c_bytes);

    hipMemsetAsync(aflags, 0, 512, stream);                  // zero both flag arrays
    cast_w1<<<1536, 256, 0, stream>>>(Wgx, Wix, Wox, Wb1);
    gemm_x<<<T_ * 8, 256, 0, stream>>>(emb, Wb1, bg, bi, bo, X);
    lstm_rec<<<128, 256, 0, stream>>>(Wgh, Wih, Woh, X, c512, aflags, aflags + 64, out);
}

// Round 3
// 4009.772 us; speedup vs baseline: 2.6130x; 1.1612x over previous
//
#include <hip/hip_runtime.h>
#include <stdint.h>

// LSTM (buggy-reference semantics): c_t = tanh(xg+Wgh c_{t-1}) * sigm(xi+Wih c_{t-1})
//                                   h_t = tanh(c_t) * sigm(xo+Woh c_{t-1});  f-gate dead.
// Phase 1: cast W*x to bf16.  Phase 2: parallel GEMM X = W*x @ emb^T + b (bf16).
// Phase 3: persistent recurrence. Round-3 changes vs round 2:
//   * ALL sync traffic (flags, chist stores, polls) at AGENT scope (L3 coherence point)
//     instead of SYSTEM scope (DRAM coherence point) -> each of the 3 per-step round
//     trips should drop from DRAM to Infinity-Cache latency.
//   * A/B blocks are 512-thr with per-wave K-split-2 so weight fragments are 128 (A)
//     / 64 (B) VGPRs per lane -> no scratch-spill risk (round 2: 256 needed, 220 reported).
// Protocol unchanged: write-once chist embedded in out rows, plain cached reads,
// per-block progress flags, vmcnt-drain before flag publication.

#define T_ 512
#define B_ 64
#define E_ 512
#define H_ 1024
#define QS ((size_t)T_ * B_ * H_)     // per-gate stride in X
#define ROWF ((size_t)(B_ * H_))      // floats per out row (65536)
#define CH_OFF (ROWF / 2)             // float offset of chist region inside an out row

typedef short bf16x8 __attribute__((ext_vector_type(8)));
typedef float f32x4  __attribute__((ext_vector_type(4)));
typedef float f32x16 __attribute__((ext_vector_type(16)));

__device__ __forceinline__ unsigned int f2bf(float f) {
    unsigned int u = __builtin_bit_cast(unsigned int, f);
    return (u + 0x7fffu + ((u >> 16) & 1u)) >> 16;   // RNE
}
__device__ __forceinline__ float bf2f(unsigned int s) {
    unsigned int u = (s & 0xffffu) << 16;
    return __builtin_bit_cast(float, u);
}
__device__ __forceinline__ float fsigm(float x) { return 1.f / (1.f + __expf(-x)); }
__device__ __forceinline__ float ftanh(float x) { float e = __expf(2.f * x); return 1.f - 2.f / (e + 1.f); }

// ---- AGENT-scope (GPU/L3 coherence point) sync primitives ----
__device__ __forceinline__ unsigned ldflag(const unsigned* p) {
    return __hip_atomic_load(p, __ATOMIC_RELAXED, __HIP_MEMORY_SCOPE_AGENT);
}
__device__ __forceinline__ void stflag(unsigned* p, unsigned v) {
    __hip_atomic_store(p, v, __ATOMIC_RELAXED, __HIP_MEMORY_SCOPE_AGENT);
}
__device__ __forceinline__ void st_ag64(void* p, unsigned long long v) {
    __hip_atomic_store((unsigned long long*)p, v, __ATOMIC_RELAXED, __HIP_MEMORY_SCOPE_AGENT);
}
__device__ __forceinline__ unsigned long long pk4bf(float a, float b, float c, float d) {
    return (unsigned long long)(f2bf(a) | (f2bf(b) << 16)) |
           ((unsigned long long)(f2bf(c) | (f2bf(d) << 16)) << 32);
}

// ---------------- Phase 1: cast Wgx/Wix/Wox -> bf16 [3][H][E] ----------------
__global__ __launch_bounds__(256) void cast_w1(const float* __restrict__ wg,
                                               const float* __restrict__ wi,
                                               const float* __restrict__ wo,
                                               unsigned short* __restrict__ dst) {
    int idx = blockIdx.x * 256 + threadIdx.x;      // each thread: 4 floats
    const int per = H_ * E_ / 4;                   // 131072
    int q = idx / per;
    int loc = (idx - q * per) * 4;
    const float* src = (q == 0) ? wg : (q == 1) ? wi : wo;
    float4 v = *(const float4*)(src + loc);
    uint2 p;
    p.x = f2bf(v.x) | (f2bf(v.y) << 16);
    p.y = f2bf(v.z) | (f2bf(v.w) << 16);
    *(uint2*)(dst + (size_t)idx * 4) = p;
}

// ---------------- Phase 2: X[q][t][b][h] = (Wq @ emb[t]^T)[h][b] + bq[h], bf16 ----------------
__global__ __launch_bounds__(256) void gemm_x(const float* __restrict__ emb,          // [T][B][E] f32
                                              const unsigned short* __restrict__ Wb1, // [3][H][E] bf16
                                              const float* __restrict__ bg,
                                              const float* __restrict__ bi,
                                              const float* __restrict__ bo,
                                              unsigned short* __restrict__ X) {       // [3][T][B][H] bf16
    const int t   = blockIdx.x >> 3;
    const int hb  = (blockIdx.x & 7) << 7;
    const int tid = threadIdx.x;
    __shared__ unsigned short eb[B_ * E_];   // 64KB, row b = 1024B, XOR-swizzled

    const float* et = emb + (size_t)t * (B_ * E_);
    #pragma unroll
    for (int it = 0; it < 32; ++it) {
        int F = (it * 256 + tid) * 4;
        int b = F >> 9, e = F & 511;
        float4 v = *(const float4*)(et + F);
        uint2 p;
        p.x = f2bf(v.x) | (f2bf(v.y) << 16);
        p.y = f2bf(v.z) | (f2bf(v.w) << 16);
        *(uint2*)((char*)eb + b * 1024 + ((e * 2) ^ ((b & 7) << 4))) = p;
    }
    __syncthreads();

    const int w = tid >> 6, l = tid & 63;
    const int l31 = l & 31, l5 = l >> 5;
    const int hw = hb + (w << 5);

    f32x16 acc[3][2];
    #pragma unroll
    for (int q = 0; q < 3; ++q)
        #pragma unroll
        for (int n = 0; n < 2; ++n)
            #pragma unroll
            for (int k = 0; k < 16; ++k) acc[q][n][k] = 0.f;

    const unsigned short* Ar0 = Wb1 + ((size_t)0 * H_ + hw + l31) * E_ + l5 * 8;
    const unsigned short* Ar1 = Wb1 + ((size_t)1 * H_ + hw + l31) * E_ + l5 * 8;
    const unsigned short* Ar2 = Wb1 + ((size_t)2 * H_ + hw + l31) * E_ + l5 * 8;

    for (int s = 0; s < 32; ++s) {
        int r0 = l31, r1 = 32 + l31;
        int c0 = (s * 32 + l5 * 16) ^ ((r0 & 7) << 4);
        int c1 = (s * 32 + l5 * 16) ^ ((r1 & 7) << 4);
        bf16x8 Bf0 = *(const bf16x8*)((const char*)eb + r0 * 1024 + c0);
        bf16x8 Bf1 = *(const bf16x8*)((const char*)eb + r1 * 1024 + c1);
        bf16x8 a0 = *(const bf16x8*)(Ar0 + s * 16);
        bf16x8 a1 = *(const bf16x8*)(Ar1 + s * 16);
        bf16x8 a2 = *(const bf16x8*)(Ar2 + s * 16);
        acc[0][0] = __builtin_amdgcn_mfma_f32_32x32x16_bf16(a0, Bf0, acc[0][0], 0, 0, 0);
        acc[0][1] = __builtin_amdgcn_mfma_f32_32x32x16_bf16(a0, Bf1, acc[0][1], 0, 0, 0);
        acc[1][0] = __builtin_amdgcn_mfma_f32_32x32x16_bf16(a1, Bf0, acc[1][0], 0, 0, 0);
        acc[1][1] = __builtin_amdgcn_mfma_f32_32x32x16_bf16(a1, Bf1, acc[1][1], 0, 0, 0);
        acc[2][0] = __builtin_amdgcn_mfma_f32_32x32x16_bf16(a2, Bf0, acc[2][0], 0, 0, 0);
        acc[2][1] = __builtin_amdgcn_mfma_f32_32x32x16_bf16(a2, Bf1, acc[2][1], 0, 0, 0);
    }

    const float* bias[3] = {bg, bi, bo};
    #pragma unroll
    for (int q = 0; q < 3; ++q) {
        #pragma unroll
        for (int g4 = 0; g4 < 4; ++g4) {
            int h = hw + g4 * 8 + l5 * 4;
            float4 bv = *(const float4*)(bias[q] + h);
            #pragma unroll
            for (int n = 0; n < 2; ++n) {
                float v0 = acc[q][n][g4 * 4 + 0] + bv.x;
                float v1 = acc[q][n][g4 * 4 + 1] + bv.y;
                float v2 = acc[q][n][g4 * 4 + 2] + bv.z;
                float v3 = acc[q][n][g4 * 4 + 3] + bv.w;
                uint2 p;
                p.x = f2bf(v0) | (f2bf(v1) << 16);
                p.y = f2bf(v2) | (f2bf(v3) << 16);
                size_t o = ((size_t)q * T_ + t) * (size_t)(B_ * H_) + (size_t)((n << 5) + l31) * H_ + h;
                *(uint2*)(X + o) = p;
            }
        }
    }
}

// ---------------- Phase 3: persistent recurrence ----------------
// 128 blocks x 512 thr. Blocks 0-63 (A): g,i -> c. Blocks 64-127 (B): o + h-emit.
// Block role-j owns h rows [16j,16j+16). Wave w: kh = w>>2 (K-half), bq = w&3 (16 b-cols).
// Weights reg-stationary: A = 128 VGPR/lane (2 gates x K/2), B = 64 VGPR/lane.
// chist[t] (carry INTO step t) = bf16[B][H] in out-row t at float offset 32768; chist[512] in ws.
// K-half partials reduced via LDS (kh=1 writes, kh=0 adds + epilogue).
__global__ __launch_bounds__(512) void lstm_rec(const float* __restrict__ Wgh,
                                                const float* __restrict__ Wih,
                                                const float* __restrict__ Woh,
                                                const unsigned short* __restrict__ X,
                                                unsigned short* __restrict__ ch512,
                                                unsigned* __restrict__ aflags,
                                                unsigned* __restrict__ bflags,
                                                float* __restrict__ out) {
    const int bid = blockIdx.x;
    const bool isA = bid < 64;
    const int blk = isA ? bid : bid - 64;
    const int h0 = blk << 4;
    const int tid = threadIdx.x;
    const int w = tid >> 6, l = tid & 63;
    const int kh = w >> 2, bq = w & 3;
    const int l15 = l & 15, l4 = l >> 4;
    const int kbase = kh << 9;                // 0 or 512
    const int bcol = (bq << 4) + l15;         // b in [0,64)
    const int hrow = h0 + (l4 << 2);          // + reg j

    __shared__ float red[4][2][64][4];        // [bq][gate][lane][reg], 8 KB

    // ---- preload recurrent-W fragments (reg-stationary for all 512 steps) ----
    // A-frag (16x16x32): row = h0 + (l&15), k = kbase + 32s + 8*(l>>4) + j
    bf16x8 Ag[16], Ai[16];
    {
        const float* r0 = (isA ? Wgh : Woh) + (size_t)(h0 + l15) * H_ + kbase + l4 * 8;
        #pragma unroll
        for (int s = 0; s < 16; ++s) {
            float4 u = *(const float4*)(r0 + s * 32);
            float4 v = *(const float4*)(r0 + s * 32 + 4);
            bf16x8 a;
            a[0] = (short)f2bf(u.x); a[1] = (short)f2bf(u.y); a[2] = (short)f2bf(u.z); a[3] = (short)f2bf(u.w);
            a[4] = (short)f2bf(v.x); a[5] = (short)f2bf(v.y); a[6] = (short)f2bf(v.z); a[7] = (short)f2bf(v.w);
            Ag[s] = a;
        }
        if (isA) {
            const float* r1 = Wih + (size_t)(h0 + l15) * H_ + kbase + l4 * 8;
            #pragma unroll
            for (int s = 0; s < 16; ++s) {
                float4 u = *(const float4*)(r1 + s * 32);
                float4 v = *(const float4*)(r1 + s * 32 + 4);
                bf16x8 a;
                a[0] = (short)f2bf(u.x); a[1] = (short)f2bf(u.y); a[2] = (short)f2bf(u.z); a[3] = (short)f2bf(u.w);
                a[4] = (short)f2bf(v.x); a[5] = (short)f2bf(v.y); a[6] = (short)f2bf(v.z); a[7] = (short)f2bf(v.w);
                Ai[s] = a;
            }
        }
    }

    if (isA) {
        for (int t = 0; t < T_; ++t) {
            // X loads hoisted before the wait (kh=0 waves only use them)
            uint2 pg = {0, 0}, pi = {0, 0};
            if (kh == 0) {
                size_t xb = ((size_t)t * B_ + bcol) * H_ + hrow;
                pg = *(const uint2*)(X + xb);
                pi = *(const uint2*)(X + xb + QS);
            }

            if (t > 0) {
                if (tid < 64) {
                    while (!__all((int)(ldflag(aflags + tid) >= (unsigned)t)))
                        __builtin_amdgcn_s_sleep(1);
                }
                __syncthreads();
            }

            f32x4 acc0 = {0.f, 0.f, 0.f, 0.f}, acc1 = {0.f, 0.f, 0.f, 0.f};
            if (t > 0) {
                const unsigned short* ct = (const unsigned short*)(out + (size_t)t * ROWF + CH_OFF);
                const unsigned short* bp = ct + (size_t)bcol * H_ + kbase + l4 * 8;
                #pragma unroll
                for (int cch = 0; cch < 2; ++cch) {
                    bf16x8 bfr[8];
                    #pragma unroll
                    for (int s = 0; s < 8; ++s) bfr[s] = *(const bf16x8*)(bp + (cch * 8 + s) * 32);
                    #pragma unroll
                    for (int s = 0; s < 8; ++s) {
                        acc0 = __builtin_amdgcn_mfma_f32_16x16x32_bf16(Ag[cch * 8 + s], bfr[s], acc0, 0, 0, 0);
                        acc1 = __builtin_amdgcn_mfma_f32_16x16x32_bf16(Ai[cch * 8 + s], bfr[s], acc1, 0, 0, 0);
                    }
                }
                // K-half reduction
                if (kh == 1) {
                    *(f32x4*)&red[bq][0][l][0] = acc0;
                    *(f32x4*)&red[bq][1][l][0] = acc1;
                }
                __syncthreads();
                if (kh == 0) {
                    acc0 += *(const f32x4*)&red[bq][0][l][0];
                    acc1 += *(const f32x4*)&red[bq][1][l][0];
                }
            }

            if (kh == 0) {
                float g0 = ftanh(acc0[0] + bf2f(pg.x));
                float g1 = ftanh(acc0[1] + bf2f(pg.x >> 16));
                float g2 = ftanh(acc0[2] + bf2f(pg.y));
                float g3 = ftanh(acc0[3] + bf2f(pg.y >> 16));
                float i0 = fsigm(acc1[0] + bf2f(pi.x));
                float i1 = fsigm(acc1[1] + bf2f(pi.x >> 16));
                float i2 = fsigm(acc1[2] + bf2f(pi.y));
                float i3 = fsigm(acc1[3] + bf2f(pi.y >> 16));
                unsigned short* cn = (t == T_ - 1) ? ch512
                                   : (unsigned short*)(out + (size_t)(t + 1) * ROWF + CH_OFF);
                st_ag64(cn + (size_t)bcol * H_ + hrow, pk4bf(g0 * i0, g1 * i1, g2 * i2, g3 * i3));
            }

            asm volatile("s_waitcnt vmcnt(0)" ::: "memory");   // per-wave drain before barrier
            __syncthreads();
            if (tid == 0) stflag(aflags + blk, (unsigned)(t + 1));
        }
    } else {
        float4 o_prev = {0.f, 0.f, 0.f, 0.f};
        for (int t = 0; t < T_; ++t) {
            uint2 po = {0, 0};
            if (kh == 0) {
                size_t xb = ((size_t)t * B_ + bcol) * H_ + hrow;
                po = *(const uint2*)(X + xb + 2 * QS);
            }

            if (t > 0) {
                if (tid < 64) {
                    while (!__all((int)(ldflag(aflags + tid) >= (unsigned)t &&
                                        ldflag(bflags + tid) >= (unsigned)t)))
                        __builtin_amdgcn_s_sleep(1);
                }
                __syncthreads();
            }

            f32x4 acc0 = {0.f, 0.f, 0.f, 0.f};
            if (t > 0) {
                const unsigned short* ct = (const unsigned short*)(out + (size_t)t * ROWF + CH_OFF);
                const unsigned short* bp = ct + (size_t)bcol * H_ + kbase + l4 * 8;
                #pragma unroll
                for (int cch = 0; cch < 2; ++cch) {
                    bf16x8 bfr[8];
                    #pragma unroll
                    for (int s = 0; s < 8; ++s) bfr[s] = *(const bf16x8*)(bp + (cch * 8 + s) * 32);
                    #pragma unroll
                    for (int s = 0; s < 8; ++s)
                        acc0 = __builtin_amdgcn_mfma_f32_16x16x32_bf16(Ag[cch * 8 + s], bfr[s], acc0, 0, 0, 0);
                }
                if (kh == 1) *(f32x4*)&red[bq][0][l][0] = acc0;
                __syncthreads();
                if (kh == 0) {
                    acc0 += *(const f32x4*)&red[bq][0][l][0];
                    // emit h_{t-1} = tanh(c_{t-1}) * o_{t-1};  c_{t-1} = chist[t]
                    uint2 pc = *(const uint2*)(ct + (size_t)bcol * H_ + hrow);
                    float4 hv;
                    hv.x = ftanh(bf2f(pc.x)) * o_prev.x;
                    hv.y = ftanh(bf2f(pc.x >> 16)) * o_prev.y;
                    hv.z = ftanh(bf2f(pc.y)) * o_prev.z;
                    hv.w = ftanh(bf2f(pc.y >> 16)) * o_prev.w;
                    *(float4*)(out + ((size_t)(t - 1) * ROWF) + (size_t)bcol * H_ + hrow) = hv;
                }
            }
            if (kh == 0) {
                o_prev.x = fsigm(acc0[0] + bf2f(po.x));
                o_prev.y = fsigm(acc0[1] + bf2f(po.x >> 16));
                o_prev.z = fsigm(acc0[2] + bf2f(po.y));
                o_prev.w = fsigm(acc0[3] + bf2f(po.y >> 16));
            }

            __syncthreads();   // chist[t] reads all consumed above -> safe to publish
            if (tid == 0) stflag(bflags + blk, (unsigned)(t + 1));
        }
        // final h_{T-1} from c_511 (= chist[512] in ws)
        if (tid < 64) {
            while (!__all((int)(ldflag(aflags + tid) >= (unsigned)T_ &&
                                ldflag(bflags + tid) >= (unsigned)T_)))
                __builtin_amdgcn_s_sleep(1);
        }
        __syncthreads();
        if (kh == 0) {
            uint2 pc = *(const uint2*)(ch512 + (size_t)bcol * H_ + hrow);
            float4 hv;
            hv.x = ftanh(bf2f(pc.x)) * o_prev.x;
            hv.y = ftanh(bf2f(pc.x >> 16)) * o_prev.y;
            hv.z = ftanh(bf2f(pc.y)) * o_prev.z;
            hv.w = ftanh(bf2f(pc.y >> 16)) * o_prev.w;
            *(float4*)(out + (size_t)(T_ - 1) * ROWF + (size_t)bcol * H_ + hrow) = hv;
        }
    }
}

extern "C" void kernel_launch(void* const* d_in, const int* in_sizes, int n_in,
                              void* d_out, int out_size, void* d_ws, size_t ws_size,
                              hipStream_t stream) {
    const float* emb = (const float*)d_in[0];
    const float* Wgx = (const float*)d_in[1];
    const float* Wgh = (const float*)d_in[2];
    const float* bg  = (const float*)d_in[3];
    const float* Wix = (const float*)d_in[4];
    const float* Wih = (const float*)d_in[5];
    const float* bi  = (const float*)d_in[6];
    // d_in[7..9] = Wfx, Wfh, bf : dead in the reference (c = g*i + 0*f)
    const float* Wox = (const float*)d_in[10];
    const float* Woh = (const float*)d_in[11];
    const float* bo  = (const float*)d_in[12];
    float* out = (float*)d_out;

    char* ws = (char*)d_ws;
    const size_t wb1_bytes = (size_t)3 * H_ * E_ * 2;        //   3.1 MB
    const size_t x_bytes   = (size_t)3 * T_ * B_ * H_ * 2;   // 201.3 MB
    const size_t c_bytes   = (size_t)B_ * H_ * 2;            // 128 KB (chist[512] only)
    unsigned short* Wb1 = (unsigned short*)ws;
    unsigned short* X   = (unsigned short*)(ws + wb1_bytes);
    unsigned short* c512 = (unsigned short*)(ws + wb1_bytes + x_bytes);
    unsigned* aflags = (unsigned*)(ws + wb1_bytes + x_bytes + c_bytes);

    hipMemsetAsync(aflags, 0, 512, stream);                  // zero both flag arrays
    cast_w1<<<1536, 256, 0, stream>>>(Wgx, Wix, Wox, Wb1);
    gemm_x<<<T_ * 8, 256, 0, stream>>>(emb, Wb1, bg, bi, bo, X);
    lstm_rec<<<128, 512, 0, stream>>>(Wgh, Wih, Woh, X, c512, aflags, aflags + 64, out);
}

// Round 5
// 3574.112 us; speedup vs baseline: 2.9315x; 1.1219x over previous
//
#include <hip/hip_runtime.h>
#include <stdint.h>

// LSTM (buggy-reference semantics): c_t = tanh(xg+Wgh c_{t-1}) * sigm(xi+Wih c_{t-1})
//                                   h_t = tanh(c_t) * sigm(xo+Woh c_{t-1});  f-gate dead.
// Phase 1: cast W*x to bf16.  Phase 2: parallel GEMM X = W*x @ emb^T + b (bf16).
// Phase 3: persistent recurrence. Round-4 change: SEQUENCER RELAY for flags.
//   Round-3 counters showed the poll fabric was the bottleneck: 128 blocks all polling
//   the same 4 flag cachelines ~430 req/us/line -> coherence-point queueing dominated
//   (6.9 us/step vs ~2 us modeled). Now: producers -> 64 padded flag lines -> ONE
//   sequencer block polls them -> writes 128 per-consumer padded GO lines -> each
//   consumer tight-spins on its OWN line (1 poller/line everywhere).
// Protocol otherwise unchanged (passed rounds 2-3): write-once chist in out rows,
// agent-scope stores, vmcnt-drain before flag publish, plain cached bulk reads.

#define T_ 512
#define B_ 64
#define E_ 512
#define H_ 1024
#define QS ((size_t)T_ * B_ * H_)     // per-gate stride in X
#define ROWF ((size_t)(B_ * H_))      // floats per out row (65536)
#define CH_OFF (ROWF / 2)             // float offset of chist region inside an out row
#define FLAG_U 32                     // uints per padded flag line (128 B)

typedef short bf16x8 __attribute__((ext_vector_type(8)));
typedef float f32x4  __attribute__((ext_vector_type(4)));
typedef float f32x16 __attribute__((ext_vector_type(16)));

__device__ __forceinline__ unsigned int f2bf(float f) {
    unsigned int u = __builtin_bit_cast(unsigned int, f);
    return (u + 0x7fffu + ((u >> 16) & 1u)) >> 16;   // RNE
}
__device__ __forceinline__ float bf2f(unsigned int s) {
    unsigned int u = (s & 0xffffu) << 16;
    return __builtin_bit_cast(float, u);
}
__device__ __forceinline__ float fsigm(float x) { return 1.f / (1.f + __expf(-x)); }
__device__ __forceinline__ float ftanh(float x) { float e = __expf(2.f * x); return 1.f - 2.f / (e + 1.f); }

__device__ __forceinline__ unsigned ldflag(const unsigned* p) {
    return __hip_atomic_load(p, __ATOMIC_RELAXED, __HIP_MEMORY_SCOPE_AGENT);
}
__device__ __forceinline__ void stflag(unsigned* p, unsigned v) {
    __hip_atomic_store(p, v, __ATOMIC_RELAXED, __HIP_MEMORY_SCOPE_AGENT);
}
__device__ __forceinline__ void st_ag64(void* p, unsigned long long v) {
    __hip_atomic_store((unsigned long long*)p, v, __ATOMIC_RELAXED, __HIP_MEMORY_SCOPE_AGENT);
}
__device__ __forceinline__ unsigned long long pk4bf(float a, float b, float c, float d) {
    return (unsigned long long)(f2bf(a) | (f2bf(b) << 16)) |
           ((unsigned long long)(f2bf(c) | (f2bf(d) << 16)) << 32);
}

// ---------------- Phase 1: cast Wgx/Wix/Wox -> bf16 [3][H][E] ----------------
__global__ __launch_bounds__(256) void cast_w1(const float* __restrict__ wg,
                                               const float* __restrict__ wi,
                                               const float* __restrict__ wo,
                                               unsigned short* __restrict__ dst) {
    int idx = blockIdx.x * 256 + threadIdx.x;      // each thread: 4 floats
    const int per = H_ * E_ / 4;                   // 131072
    int q = idx / per;
    int loc = (idx - q * per) * 4;
    const float* src = (q == 0) ? wg : (q == 1) ? wi : wo;
    float4 v = *(const float4*)(src + loc);
    uint2 p;
    p.x = f2bf(v.x) | (f2bf(v.y) << 16);
    p.y = f2bf(v.z) | (f2bf(v.w) << 16);
    *(uint2*)(dst + (size_t)idx * 4) = p;
}

// ---------------- Phase 2: X[q][t][b][h] = (Wq @ emb[t]^T)[h][b] + bq[h], bf16 ----------------
__global__ __launch_bounds__(256) void gemm_x(const float* __restrict__ emb,          // [T][B][E] f32
                                              const unsigned short* __restrict__ Wb1, // [3][H][E] bf16
                                              const float* __restrict__ bg,
                                              const float* __restrict__ bi,
                                              const float* __restrict__ bo,
                                              unsigned short* __restrict__ X) {       // [3][T][B][H] bf16
    const int t   = blockIdx.x >> 3;
    const int hb  = (blockIdx.x & 7) << 7;
    const int tid = threadIdx.x;
    __shared__ unsigned short eb[B_ * E_];   // 64KB, row b = 1024B, XOR-swizzled

    const float* et = emb + (size_t)t * (B_ * E_);
    #pragma unroll
    for (int it = 0; it < 32; ++it) {
        int F = (it * 256 + tid) * 4;
        int b = F >> 9, e = F & 511;
        float4 v = *(const float4*)(et + F);
        uint2 p;
        p.x = f2bf(v.x) | (f2bf(v.y) << 16);
        p.y = f2bf(v.z) | (f2bf(v.w) << 16);
        *(uint2*)((char*)eb + b * 1024 + ((e * 2) ^ ((b & 7) << 4))) = p;
    }
    __syncthreads();

    const int w = tid >> 6, l = tid & 63;
    const int l31 = l & 31, l5 = l >> 5;
    const int hw = hb + (w << 5);

    f32x16 acc[3][2];
    #pragma unroll
    for (int q = 0; q < 3; ++q)
        #pragma unroll
        for (int n = 0; n < 2; ++n)
            #pragma unroll
            for (int k = 0; k < 16; ++k) acc[q][n][k] = 0.f;

    const unsigned short* Ar0 = Wb1 + ((size_t)0 * H_ + hw + l31) * E_ + l5 * 8;
    const unsigned short* Ar1 = Wb1 + ((size_t)1 * H_ + hw + l31) * E_ + l5 * 8;
    const unsigned short* Ar2 = Wb1 + ((size_t)2 * H_ + hw + l31) * E_ + l5 * 8;

    for (int s = 0; s < 32; ++s) {
        int r0 = l31, r1 = 32 + l31;
        int c0 = (s * 32 + l5 * 16) ^ ((r0 & 7) << 4);
        int c1 = (s * 32 + l5 * 16) ^ ((r1 & 7) << 4);
        bf16x8 Bf0 = *(const bf16x8*)((const char*)eb + r0 * 1024 + c0);
        bf16x8 Bf1 = *(const bf16x8*)((const char*)eb + r1 * 1024 + c1);
        bf16x8 a0 = *(const bf16x8*)(Ar0 + s * 16);
        bf16x8 a1 = *(const bf16x8*)(Ar1 + s * 16);
        bf16x8 a2 = *(const bf16x8*)(Ar2 + s * 16);
        acc[0][0] = __builtin_amdgcn_mfma_f32_32x32x16_bf16(a0, Bf0, acc[0][0], 0, 0, 0);
        acc[0][1] = __builtin_amdgcn_mfma_f32_32x32x16_bf16(a0, Bf1, acc[0][1], 0, 0, 0);
        acc[1][0] = __builtin_amdgcn_mfma_f32_32x32x16_bf16(a1, Bf0, acc[1][0], 0, 0, 0);
        acc[1][1] = __builtin_amdgcn_mfma_f32_32x32x16_bf16(a1, Bf1, acc[1][1], 0, 0, 0);
        acc[2][0] = __builtin_amdgcn_mfma_f32_32x32x16_bf16(a2, Bf0, acc[2][0], 0, 0, 0);
        acc[2][1] = __builtin_amdgcn_mfma_f32_32x32x16_bf16(a2, Bf1, acc[2][1], 0, 0, 0);
    }

    const float* bias[3] = {bg, bi, bo};
    #pragma unroll
    for (int q = 0; q < 3; ++q) {
        #pragma unroll
        for (int g4 = 0; g4 < 4; ++g4) {
            int h = hw + g4 * 8 + l5 * 4;
            float4 bv = *(const float4*)(bias[q] + h);
            #pragma unroll
            for (int n = 0; n < 2; ++n) {
                float v0 = acc[q][n][g4 * 4 + 0] + bv.x;
                float v1 = acc[q][n][g4 * 4 + 1] + bv.y;
                float v2 = acc[q][n][g4 * 4 + 2] + bv.z;
                float v3 = acc[q][n][g4 * 4 + 3] + bv.w;
                uint2 p;
                p.x = f2bf(v0) | (f2bf(v1) << 16);
                p.y = f2bf(v2) | (f2bf(v3) << 16);
                size_t o = ((size_t)q * T_ + t) * (size_t)(B_ * H_) + (size_t)((n << 5) + l31) * H_ + h;
                *(uint2*)(X + o) = p;
            }
        }
    }
}

// ---------------- Phase 3: persistent recurrence with sequencer relay ----------------
// 129 blocks x 512 thr. Block 0: sequencer. Blocks 1-64 (A): g,i -> c. 65-128 (B): o + h.
// A/B role-j owns h rows [16j,16j+16). Wave w: kh = w>>2 (K-half), bq = w&3 (16 b-cols).
// Padded flag lines (128B each): aflag[64], bflag[64], go[128] (goA = go[0..63], goB = go[64..127]).
// Sequencer: for u=1..512: spin until all aflag>=u -> write goA[j]=u (64 lines);
//            spin until all bflag>=u -> write goB[j]=u.
// Consumers tight-spin on their OWN go line only (1 poller per line everywhere).
__global__ __launch_bounds__(512) void lstm_rec(const float* __restrict__ Wgh,
                                                const float* __restrict__ Wih,
                                                const float* __restrict__ Woh,
                                                const unsigned short* __restrict__ X,
                                                unsigned short* __restrict__ ch512,
                                                unsigned* __restrict__ flagbase,
                                                float* __restrict__ out) {
    unsigned* aflagp = flagbase;                      // 64 lines
    unsigned* bflagp = flagbase + 64 * FLAG_U;        // 64 lines
    unsigned* gop    = flagbase + 128 * FLAG_U;       // 128 lines

    const int bid = blockIdx.x;
    const int tid = threadIdx.x;

    if (bid == 0) {
        // ---- sequencer: wave 0 only ----
        if (tid < 64) {
            for (int u = 1; u <= T_; ++u) {
                while (!__all((int)(ldflag(aflagp + tid * FLAG_U) >= (unsigned)u))) {}
                stflag(gop + tid * FLAG_U, (unsigned)u);                 // goA[tid] = u
                while (!__all((int)(ldflag(bflagp + tid * FLAG_U) >= (unsigned)u))) {}
                stflag(gop + (64 + tid) * FLAG_U, (unsigned)u);          // goB[tid] = u
            }
        }
        return;
    }

    const bool isA = bid <= 64;
    const int blk = isA ? bid - 1 : bid - 65;
    const int h0 = blk << 4;
    const int w = tid >> 6, l = tid & 63;
    const int kh = w >> 2, bq = w & 3;
    const int l15 = l & 15, l4 = l >> 4;
    const int kbase = kh << 9;                // 0 or 512
    const int bcol = (bq << 4) + l15;         // b in [0,64)
    const int hrow = h0 + (l4 << 2);          // + reg j
    unsigned* myflag = (isA ? aflagp : bflagp) + blk * FLAG_U;
    const unsigned* mygo = gop + (isA ? blk : 64 + blk) * FLAG_U;

    __shared__ float red[4][2][64][4];        // [bq][gate][lane][reg], 8 KB

    // ---- preload recurrent-W fragments (reg-stationary for all 512 steps) ----
    // A-frag (16x16x32): row = h0 + (l&15), k = kbase + 32s + 8*(l>>4) + j
    bf16x8 Ag[16], Ai[16];
    {
        const float* r0 = (isA ? Wgh : Woh) + (size_t)(h0 + l15) * H_ + kbase + l4 * 8;
        #pragma unroll
        for (int s = 0; s < 16; ++s) {
            float4 u = *(const float4*)(r0 + s * 32);
            float4 v = *(const float4*)(r0 + s * 32 + 4);
            bf16x8 a;
            a[0] = (short)f2bf(u.x); a[1] = (short)f2bf(u.y); a[2] = (short)f2bf(u.z); a[3] = (short)f2bf(u.w);
            a[4] = (short)f2bf(v.x); a[5] = (short)f2bf(v.y); a[6] = (short)f2bf(v.z); a[7] = (short)f2bf(v.w);
            Ag[s] = a;
        }
        if (isA) {
            const float* r1 = Wih + (size_t)(h0 + l15) * H_ + kbase + l4 * 8;
            #pragma unroll
            for (int s = 0; s < 16; ++s) {
                float4 u = *(const float4*)(r1 + s * 32);
                float4 v = *(const float4*)(r1 + s * 32 + 4);
                bf16x8 a;
                a[0] = (short)f2bf(u.x); a[1] = (short)f2bf(u.y); a[2] = (short)f2bf(u.z); a[3] = (short)f2bf(u.w);
                a[4] = (short)f2bf(v.x); a[5] = (short)f2bf(v.y); a[6] = (short)f2bf(v.z); a[7] = (short)f2bf(v.w);
                Ai[s] = a;
            }
        }
    }

    if (isA) {
        for (int t = 0; t < T_; ++t) {
            uint2 pg = {0, 0}, pi = {0, 0};
            if (kh == 0) {
                size_t xb = ((size_t)t * B_ + bcol) * H_ + hrow;
                pg = *(const uint2*)(X + xb);          // hoisted: independent of carry
                pi = *(const uint2*)(X + xb + QS);
            }

            if (t > 0) {
                if (tid == 0) { while (ldflag(mygo) < (unsigned)t) {} }
                __syncthreads();
            }

            f32x4 acc0 = {0.f, 0.f, 0.f, 0.f}, acc1 = {0.f, 0.f, 0.f, 0.f};
            if (t > 0) {
                const unsigned short* ct = (const unsigned short*)(out + (size_t)t * ROWF + CH_OFF);
                const unsigned short* bp = ct + (size_t)bcol * H_ + kbase + l4 * 8;
                #pragma unroll
                for (int cch = 0; cch < 2; ++cch) {
                    bf16x8 bfr[8];
                    #pragma unroll
                    for (int s = 0; s < 8; ++s) bfr[s] = *(const bf16x8*)(bp + (cch * 8 + s) * 32);
                    #pragma unroll
                    for (int s = 0; s < 8; ++s) {
                        acc0 = __builtin_amdgcn_mfma_f32_16x16x32_bf16(Ag[cch * 8 + s], bfr[s], acc0, 0, 0, 0);
                        acc1 = __builtin_amdgcn_mfma_f32_16x16x32_bf16(Ai[cch * 8 + s], bfr[s], acc1, 0, 0, 0);
                    }
                }
                if (kh == 1) {
                    *(f32x4*)&red[bq][0][l][0] = acc0;
                    *(f32x4*)&red[bq][1][l][0] = acc1;
                }
                __syncthreads();
                if (kh == 0) {
                    acc0 += *(const f32x4*)&red[bq][0][l][0];
                    acc1 += *(const f32x4*)&red[bq][1][l][0];
                }
            }

            if (kh == 0) {
                float g0 = ftanh(acc0[0] + bf2f(pg.x));
                float g1 = ftanh(acc0[1] + bf2f(pg.x >> 16));
                float g2 = ftanh(acc0[2] + bf2f(pg.y));
                float g3 = ftanh(acc0[3] + bf2f(pg.y >> 16));
                float i0 = fsigm(acc1[0] + bf2f(pi.x));
                float i1 = fsigm(acc1[1] + bf2f(pi.x >> 16));
                float i2 = fsigm(acc1[2] + bf2f(pi.y));
                float i3 = fsigm(acc1[3] + bf2f(pi.y >> 16));
                unsigned short* cn = (t == T_ - 1) ? ch512
                                   : (unsigned short*)(out + (size_t)(t + 1) * ROWF + CH_OFF);
                st_ag64(cn + (size_t)bcol * H_ + hrow, pk4bf(g0 * i0, g1 * i1, g2 * i2, g3 * i3));
            }

            asm volatile("s_waitcnt vmcnt(0)" ::: "memory");   // per-wave drain before barrier
            __syncthreads();
            if (tid == 0) stflag(myflag, (unsigned)(t + 1));
        }
    } else {
        float4 o_prev = {0.f, 0.f, 0.f, 0.f};
        for (int t = 0; t < T_; ++t) {
            uint2 po = {0, 0};
            if (kh == 0) {
                size_t xb = ((size_t)t * B_ + bcol) * H_ + hrow;
                po = *(const uint2*)(X + xb + 2 * QS);
            }

            if (t > 0) {
                if (tid == 0) { while (ldflag(mygo) < (unsigned)t) {} }
                __syncthreads();
            }

            f32x4 acc0 = {0.f, 0.f, 0.f, 0.f};
            if (t > 0) {
                const unsigned short* ct = (const unsigned short*)(out + (size_t)t * ROWF + CH_OFF);
                const unsigned short* bp = ct + (size_t)bcol * H_ + kbase + l4 * 8;
                #pragma unroll
                for (int cch = 0; cch < 2; ++cch) {
                    bf16x8 bfr[8];
                    #pragma unroll
                    for (int s = 0; s < 8; ++s) bfr[s] = *(const bf16x8*)(bp + (cch * 8 + s) * 32);
                    #pragma unroll
                    for (int s = 0; s < 8; ++s)
                        acc0 = __builtin_amdgcn_mfma_f32_16x16x32_bf16(Ag[cch * 8 + s], bfr[s], acc0, 0, 0, 0);
                }
                if (kh == 1) *(f32x4*)&red[bq][0][l][0] = acc0;
                __syncthreads();
                if (kh == 0) {
                    acc0 += *(const f32x4*)&red[bq][0][l][0];
                    // emit h_{t-1} = tanh(c_{t-1}) * o_{t-1};  c_{t-1} = chist[t]
                    uint2 pc = *(const uint2*)(ct + (size_t)bcol * H_ + hrow);
                    float4 hv;
                    hv.x = ftanh(bf2f(pc.x)) * o_prev.x;
                    hv.y = ftanh(bf2f(pc.x >> 16)) * o_prev.y;
                    hv.z = ftanh(bf2f(pc.y)) * o_prev.z;
                    hv.w = ftanh(bf2f(pc.y >> 16)) * o_prev.w;
                    *(float4*)(out + ((size_t)(t - 1) * ROWF) + (size_t)bcol * H_ + hrow) = hv;
                }
            }
            if (kh == 0) {
                o_prev.x = fsigm(acc0[0] + bf2f(po.x));
                o_prev.y = fsigm(acc0[1] + bf2f(po.x >> 16));
                o_prev.z = fsigm(acc0[2] + bf2f(po.y));
                o_prev.w = fsigm(acc0[3] + bf2f(po.y >> 16));
            }

            __syncthreads();   // chist[t] reads all consumed above -> safe to publish
            if (tid == 0) stflag(myflag, (unsigned)(t + 1));
        }
        // final h_{T-1} from c_511 (= chist[512] in ws); goB==512 implies aflags,bflags==512
        if (tid == 0) { while (ldflag(mygo) < (unsigned)T_) {} }
        __syncthreads();
        if (kh == 0) {
            uint2 pc = *(const uint2*)(ch512 + (size_t)bcol * H_ + hrow);
            float4 hv;
            hv.x = ftanh(bf2f(pc.x)) * o_prev.x;
            hv.y = ftanh(bf2f(pc.x >> 16)) * o_prev.y;
            hv.z = ftanh(bf2f(pc.y)) * o_prev.z;
            hv.w = ftanh(bf2f(pc.y >> 16)) * o_prev.w;
            *(float4*)(out + (size_t)(T_ - 1) * ROWF + (size_t)bcol * H_ + hrow) = hv;
        }
    }
}

extern "C" void kernel_launch(void* const* d_in, const int* in_sizes, int n_in,
                              void* d_out, int out_size, void* d_ws, size_t ws_size,
                              hipStream_t stream) {
    const float* emb = (const float*)d_in[0];
    const float* Wgx = (const float*)d_in[1];
    const float* Wgh = (const float*)d_in[2];
    const float* bg  = (const float*)d_in[3];
    const float* Wix = (const float*)d_in[4];
    const float* Wih = (const float*)d_in[5];
    const float* bi  = (const float*)d_in[6];
    // d_in[7..9] = Wfx, Wfh, bf : dead in the reference (c = g*i + 0*f)
    const float* Wox = (const float*)d_in[10];
    const float* Woh = (const float*)d_in[11];
    const float* bo  = (const float*)d_in[12];
    float* out = (float*)d_out;

    char* ws = (char*)d_ws;
    const size_t wb1_bytes  = (size_t)3 * H_ * E_ * 2;        //   3.1 MB
    const size_t x_bytes    = (size_t)3 * T_ * B_ * H_ * 2;   // 201.3 MB
    const size_t c_bytes    = (size_t)B_ * H_ * 2;            // 128 KB (chist[512] only)
    const size_t flag_bytes = (size_t)(64 + 64 + 128) * FLAG_U * 4;  // 32 KB padded lines
    unsigned short* Wb1 = (unsigned short*)ws;
    unsigned short* X   = (unsigned short*)(ws + wb1_bytes);
    unsigned short* c512 = (unsigned short*)(ws + wb1_bytes + x_bytes);
    unsigned* flagbase = (unsigned*)(ws + wb1_bytes + x_bytes + c_bytes);

    hipMemsetAsync(flagbase, 0, flag_bytes, stream);
    cast_w1<<<1536, 256, 0, stream>>>(Wgx, Wix, Wox, Wb1);
    gemm_x<<<T_ * 8, 256, 0, stream>>>(emb, Wb1, bg, bi, bo, X);
    lstm_rec<<<129, 512, 0, stream>>>(Wgh, Wih, Woh, X, c512, flagbase, out);
}